// Round 3
// baseline (77.474 us; speedup 1.0000x reference)
//
#include <hip/hip_runtime.h>

#define BB 8
#define CC 384
#define HH 64
#define WW 64
#define NH 6
#define HD 64
#define PLANE (HH*WW)   /* 4096 */
#define QKSCALE 0.125f
#define DW 16            /* d-slice per wave */
#define DCHUNK 8

__global__ __launch_bounds__(256, 8) void dilate_attn_kernel(
    const float* __restrict__ qg, const float* __restrict__ kg,
    const float* __restrict__ vg, float* __restrict__ outg) {
  const int blk  = blockIdx.x;
  const int y    = blk % HH;
  const int bh   = blk / HH;           // b*NH + head
  const int head = bh % NH;
  const int b    = bh / NH;
  const int lane = threadIdx.x & 63;   // x
  const int w    = threadIdx.x >> 6;   // d-slice index, 0..3
  const int x = lane;

  const int laneL = (lane - 1) & 63;   // srcLane for value at x-1 (wraps, masked)
  const int laneR = (lane + 1) & 63;   // srcLane for value at x+1

  const long slab = ((long)(b * CC + head * HD) + (long)w * DW) * PLANE;
  const float* qs = qg + slab + y * WW + x;

  // 3 row bases (clamped) + validity masks m[r][dx]
  const float* krow[3];
  const float* vrow[3];
  float m[9];
#pragma unroll
  for (int r = 0; r < 3; ++r) {
    const int yy = y + r - 1;
    const int yc = min(max(yy, 0), HH - 1);
    krow[r] = kg + slab + yc * WW + x;
    vrow[r] = vg + slab + yc * WW + x;
    const bool rowok = (yy >= 0) && (yy < HH);
#pragma unroll
    for (int dx = 0; dx < 3; ++dx) {
      const int xx = x + dx - 1;
      m[r * 3 + dx] = (rowok && xx >= 0 && xx < WW) ? 1.0f : 0.0f;
    }
  }

  // ---- QK^T partials over this wave's 16 channels ----
  // t[r][dx](x) = sum_d k_r,d(x) * q_d(x - dx)
  float t[9];
#pragma unroll
  for (int i = 0; i < 9; ++i) t[i] = 0.0f;

#pragma unroll
  for (int d0 = 0; d0 < DW; d0 += DCHUNK) {
    float qv[DCHUNK], kv[3][DCHUNK];
#pragma unroll
    for (int dd = 0; dd < DCHUNK; ++dd) qv[dd] = qs[(d0 + dd) * PLANE];
#pragma unroll
    for (int r = 0; r < 3; ++r)
#pragma unroll
      for (int dd = 0; dd < DCHUNK; ++dd) kv[r][dd] = krow[r][(d0 + dd) * PLANE];

#pragma unroll
    for (int dd = 0; dd < DCHUNK; ++dd) {
      const float qc = qv[dd];
      const float qm = __shfl(qc, laneL);  // q(x-1)
      const float qp = __shfl(qc, laneR);  // q(x+1)
#pragma unroll
      for (int r = 0; r < 3; ++r) {
        const float kc = kv[r][dd];
        t[r * 3 + 0] = fmaf(kc, qp, t[r * 3 + 0]);  // dx=-1 uses q(x+1)
        t[r * 3 + 1] = fmaf(kc, qc, t[r * 3 + 1]);  // dx= 0
        t[r * 3 + 2] = fmaf(kc, qm, t[r * 3 + 2]);  // dx=+1 uses q(x-1)
      }
    }
  }

  // ---- cross-wave d-reduction through LDS (one barrier) ----
  __shared__ float red[9][4][64];
#pragma unroll
  for (int i = 0; i < 9; ++i) red[i][w][lane] = t[i];
  __syncthreads();

  float s[9];
#pragma unroll
  for (int i = 0; i < 9; ++i) {
    const float tsum = red[i][0][lane] + red[i][1][lane] +
                       red[i][2][lane] + red[i][3][lane];
    const int dx = (i % 3) - 1;
    // gather: s[r,dx](x) = t[r,dx](x+dx), then mask + scale
    s[i] = __shfl(tsum, (lane + dx) & 63) * m[i] * QKSCALE;
  }

  // softmax over 9 (masked entries exactly 0, matching zero-padded ref)
  float mx = s[0];
#pragma unroll
  for (int i = 1; i < 9; ++i) mx = fmaxf(mx, s[i]);
  float sum = 0.0f;
#pragma unroll
  for (int i = 0; i < 9; ++i) { s[i] = __expf(s[i] - mx); sum += s[i]; }
  const float inv = 1.0f / sum;
#pragma unroll
  for (int i = 0; i < 9; ++i) s[i] = s[i] * inv * m[i];  // fold v-pad mask into p

  // pre-shift p: P[r,dx](j) = p[r,dx](j - dx), zero out-of-image edge lanes
  float P[9];
#pragma unroll
  for (int i = 0; i < 9; ++i) {
    const int dx = (i % 3) - 1;
    float pe = __shfl(s[i], (lane - dx) & 63);
    if (dx == 1 && lane == 0) pe = 0.0f;
    if (dx == -1 && lane == 63) pe = 0.0f;
    P[i] = pe;
  }

  // ---- PV over this wave's 16 channels ----
  float* outp = outg + ((long)((b * HH + y) * WW + x)) * CC + head * HD + w * DW;

#pragma unroll
  for (int d0 = 0; d0 < DW; d0 += DCHUNK) {
    float vv[3][DCHUNK];
#pragma unroll
    for (int r = 0; r < 3; ++r)
#pragma unroll
      for (int dd = 0; dd < DCHUNK; ++dd) vv[r][dd] = vrow[r][(d0 + dd) * PLANE];

    float o[DCHUNK];
#pragma unroll
    for (int dd = 0; dd < DCHUNK; ++dd) {
      float cm = 0.f, c0 = 0.f, cp = 0.f;
#pragma unroll
      for (int r = 0; r < 3; ++r) {
        const float vc = vv[r][dd];
        cm = fmaf(P[r * 3 + 0], vc, cm);
        c0 = fmaf(P[r * 3 + 1], vc, c0);
        cp = fmaf(P[r * 3 + 2], vc, cp);
      }
      o[dd] = c0 + __shfl(cm, laneL) + __shfl(cp, laneR);
    }
#pragma unroll
    for (int dd = 0; dd < DCHUNK; dd += 4) {
      float4 ov; ov.x = o[dd]; ov.y = o[dd + 1]; ov.z = o[dd + 2]; ov.w = o[dd + 3];
      *reinterpret_cast<float4*>(outp + d0 + dd) = ov;
    }
  }
}

extern "C" void kernel_launch(void* const* d_in, const int* in_sizes, int n_in,
                              void* d_out, int out_size, void* d_ws, size_t ws_size,
                              hipStream_t stream) {
  const float* q = (const float*)d_in[0];
  const float* k = (const float*)d_in[1];
  const float* v = (const float*)d_in[2];
  float* out = (float*)d_out;
  const int blocks = BB * NH * HH;  // 3072, one (b,head,y) row per block
  dilate_attn_kernel<<<blocks, 256, 0, stream>>>(q, k, v, out);
}